// Round 3
// baseline (183.899 us; speedup 1.0000x reference)
//
#include <hip/hip_runtime.h>

// LSTM B=32768, T=50, I=2, H=32. 2048 blocks x 128 threads (2 waves / 16 rows).
// Wave w computes gate-tiles n in {w, 2+w, 4+w, 6+w}: all 4 gates for units
// w*16..w*16+15 -> activations fully in-register, no cross-wave z exchange.
// h round-trips LDS as packed (lo16|hi16) u32, DOUBLE-BUFFERED -> 1 barrier/t.
// Recurrent GEMM: mfma_f32_16x16x32_bf16 split precision (hh*Wh+hl*Wh+hh*Wl).
// Output head = 3 MFMAs vs replicated W_out B-frag on the same A-fragment.
// Gate scales (-log2e / +2log2e) folded into W/bias; per set: 5 exp2 + 2 rcp.

#define TS 50
#define HSTR 36            // u32 stride of hpk rows (144B, 16B-aligned)
#define HBUF (16 * HSTR)   // one h buffer

typedef short short8 __attribute__((ext_vector_type(8)));
typedef float f32x4 __attribute__((ext_vector_type(4)));

__device__ __forceinline__ float fast_exp2(float x) {
    return __builtin_amdgcn_exp2f(x);
}
__device__ __forceinline__ float fast_rcp(float x) {
    return __builtin_amdgcn_rcpf(x);
}
// v ~= hi + lo (bf16 each, trunc): returns (lo<<16)|hi in 3 VALU
__device__ __forceinline__ unsigned split_pack(float v) {
    unsigned u   = __float_as_uint(v);
    float    res = v - __uint_as_float(u & 0xffff0000u);
    return __builtin_amdgcn_perm(__float_as_uint(res), u, 0x07060302u);
}
// (a & 0xffff) | (b << 16)
__device__ __forceinline__ unsigned lo_pair(unsigned a, unsigned b) {
    return __builtin_amdgcn_perm(b, a, 0x05040100u);
}
// (a >> 16) | (b & 0xffff0000)
__device__ __forceinline__ unsigned hi_pair(unsigned a, unsigned b) {
    return __builtin_amdgcn_perm(b, a, 0x07060302u);
}

__global__ __launch_bounds__(128, 4)
void lsnn_kernel(const float* __restrict__ x,
                 const float* __restrict__ W_ih,
                 const float* __restrict__ W_hh,
                 const float* __restrict__ b_ih,
                 const float* __restrict__ b_hh,
                 const float* __restrict__ W_out,
                 const float* __restrict__ b_out,
                 const float* __restrict__ h0,
                 const float* __restrict__ c0,
                 float* __restrict__ out)
{
    __shared__ __align__(16) float    x_lds[16 * 100];   // 6400 B
    __shared__ __align__(16) unsigned hpk[2 * HBUF];     // 4608 B, dbuf
    __shared__ __align__(16) float    out_lds[16 * TS];  // 3200 B

    const int tid  = threadIdx.x;
    const int w    = tid >> 6;     // wave: unit-half
    const int lane = tid & 63;
    const int u0   = lane & 15;    // C col / A row (batch row)
    const int q    = lane >> 4;    // quad
    const long b0  = (long)blockIdx.x * 16;

    // ---- stage x: 1600 contiguous floats ----
    {
        const float4* xs = (const float4*)(x + b0 * 100);
        float4* xd = (float4*)x_lds;
        for (int i = tid; i < 400; i += 128) xd[i] = xs[i];
    }
    // ---- init packed h0 into buffer 0 ----
    for (int i = tid; i < 512; i += 128) {
        int r = i >> 5, u = i & 31;
        hpk[r * HSTR + u] = split_pack(h0[b0 * 32 + i]);
    }

    const float L2E = 1.4426950408889634f;
    const float SG  = 2.0f * L2E;

    // ---- per-wave B-tiles: gates j=0..3 (i,f,g,o), unit-half w ----
    short8 Bh[4], Bl[4];
    float bias[4], wx0[4], wx1[4];
    #pragma unroll
    for (int j = 0; j < 4; ++j) {
        const int   n = 2 * j + w;
        const float s = (j == 2) ? (2.0f * L2E) : -L2E;
        const int   g = n * 16 + u0;
        const float* wr = W_hh + g * 32 + q * 8;
        union { unsigned u[4]; short8 s8; } uh, ul;
        #pragma unroll
        for (int p = 0; p < 4; ++p) {
            unsigned p0 = split_pack(wr[2*p]   * s);
            unsigned p1 = split_pack(wr[2*p+1] * s);
            uh.u[p] = lo_pair(p0, p1);
            ul.u[p] = hi_pair(p0, p1);
        }
        Bh[j] = uh.s8; Bl[j] = ul.s8;
        bias[j] = (b_ih[g] + b_hh[g]) * s;
        wx0[j]  = W_ih[g * 2 + 0] * s;
        wx1[j]  = W_ih[g * 2 + 1] * s;
    }
    // ---- head B-frag (wave 0 only): B[k][n] = w_out[k] for all n ----
    short8 Bwh = {}, Bwl = {};
    if (w == 0) {
        union { unsigned u[4]; short8 s8; } uh, ul;
        #pragma unroll
        for (int p = 0; p < 4; ++p) {
            unsigned p0 = split_pack(W_out[q * 8 + 2*p]);
            unsigned p1 = split_pack(W_out[q * 8 + 2*p + 1]);
            uh.u[p] = lo_pair(p0, p1);
            ul.u[p] = hi_pair(p0, p1);
        }
        Bwh = uh.s8; Bwl = ul.s8;
    }
    const float bout = b_out[0];

    // ---- c-state: rows q*4+r, unit w*16+u0 ----
    float cst[4];
    #pragma unroll
    for (int r = 0; r < 4; ++r)
        cst[r] = c0[(b0 + q * 4 + r) * 32 + w * 16 + u0];

    __syncthreads();

    const int abase = u0 * HSTR + q * 8;

    #pragma unroll 1
    for (int t = 0; t < TS; ++t) {
        const unsigned* rb = hpk + (t & 1) * HBUF;
        unsigned*       wb = hpk + ((t & 1) ^ 1) * HBUF;

        // ---- A-fragment h_{t-1}: row u0, k = q*8..q*8+7 ----
        uint4 hq0 = *(const uint4*)(rb + abase);
        uint4 hq1 = *(const uint4*)(rb + abase + 4);
        union { unsigned u[4]; short8 s8; } Ahh, Ahl;
        Ahh.u[0] = lo_pair(hq0.x, hq0.y); Ahh.u[1] = lo_pair(hq0.z, hq0.w);
        Ahh.u[2] = lo_pair(hq1.x, hq1.y); Ahh.u[3] = lo_pair(hq1.z, hq1.w);
        Ahl.u[0] = hi_pair(hq0.x, hq0.y); Ahl.u[1] = hi_pair(hq0.z, hq0.w);
        Ahl.u[2] = hi_pair(hq1.x, hq1.y); Ahl.u[3] = hi_pair(hq1.z, hq1.w);

        // ---- xg (exact fp32) as C-operand ----
        float xr0[4], xr1[4];
        #pragma unroll
        for (int r = 0; r < 4; ++r) {
            float2 xv = *(const float2*)&x_lds[(q * 4 + r) * 100 + 2 * t];
            xr0[r] = xv.x; xr1[r] = xv.y;
        }
        f32x4 acc[4];
        #pragma unroll
        for (int j = 0; j < 4; ++j) {
            f32x4 ci;
            #pragma unroll
            for (int r = 0; r < 4; ++r)
                ci[r] = fmaf(wx1[j], xr1[r], fmaf(wx0[j], xr0[r], bias[j]));
            acc[j] = __builtin_amdgcn_mfma_f32_16x16x32_bf16(Ahh.s8, Bh[j], ci,     0, 0, 0);
            acc[j] = __builtin_amdgcn_mfma_f32_16x16x32_bf16(Ahl.s8, Bh[j], acc[j], 0, 0, 0);
            acc[j] = __builtin_amdgcn_mfma_f32_16x16x32_bf16(Ahh.s8, Bl[j], acc[j], 0, 0, 0);
        }

        // ---- output head for h_{t-1} (wave 0): D[m][n] = sum_k h[m,k] w[k] ----
        if (w == 0 && t > 0) {
            f32x4 aw = {0.f, 0.f, 0.f, 0.f};
            aw = __builtin_amdgcn_mfma_f32_16x16x32_bf16(Ahh.s8, Bwh, aw, 0, 0, 0);
            aw = __builtin_amdgcn_mfma_f32_16x16x32_bf16(Ahl.s8, Bwh, aw, 0, 0, 0);
            aw = __builtin_amdgcn_mfma_f32_16x16x32_bf16(Ahh.s8, Bwl, aw, 0, 0, 0);
            if (u0 == 0) {
                #pragma unroll
                for (int r = 0; r < 4; ++r)
                    out_lds[(q * 4 + r) * TS + (t - 1)] = aw[r] + bout;
            }
        }

        // ---- activations: 4 (row, unit) sets, in-register ----
        #pragma unroll
        for (int r = 0; r < 4; ++r) {
            float zi = fminf(acc[0][r], 30.f);
            float zf = fminf(acc[1][r], 30.f);
            float zg = fminf(acc[2][r], 30.f);
            float zo = fminf(acc[3][r], 30.f);
            float Av = fast_exp2(zi);
            float Bv = fast_exp2(zg);
            float Ev = fast_exp2(zf);
            float Ap = 1.0f + Av, Bp = 1.0f + Bv, Ep = 1.0f + Ev;
            float P1 = Ap * Bp;
            float R  = fast_rcp(P1 * Ep);
            float ig = (Bv - 1.0f) * (Ep * R);   // sigmoid(i)*tanh(g)
            float fv = P1 * R;                   // sigmoid(f)
            float c  = fmaf(fv, cst[r], ig);
            cst[r] = c;
            float Cv = fast_exp2(zo);
            float Dv = fast_exp2(fminf(SG * c, 30.f));
            float R2 = fast_rcp((1.0f + Cv) * (1.0f + Dv));
            float h  = (Dv - 1.0f) * R2;         // sigmoid(o)*tanh(c)
            wb[(q * 4 + r) * HSTR + w * 16 + u0] = split_pack(h);
        }

        __syncthreads();   // h_t visible before next iteration's reads
    }

    // ---- final head for h_49 (in buffer TS&1 = 0) ----
    if (w == 0) {
        const unsigned* rb = hpk + (TS & 1) * HBUF;
        uint4 hq0 = *(const uint4*)(rb + abase);
        uint4 hq1 = *(const uint4*)(rb + abase + 4);
        union { unsigned u[4]; short8 s8; } Ahh, Ahl;
        Ahh.u[0] = lo_pair(hq0.x, hq0.y); Ahh.u[1] = lo_pair(hq0.z, hq0.w);
        Ahh.u[2] = lo_pair(hq1.x, hq1.y); Ahh.u[3] = lo_pair(hq1.z, hq1.w);
        Ahl.u[0] = hi_pair(hq0.x, hq0.y); Ahl.u[1] = hi_pair(hq0.z, hq0.w);
        Ahl.u[2] = hi_pair(hq1.x, hq1.y); Ahl.u[3] = hi_pair(hq1.z, hq1.w);
        f32x4 aw = {0.f, 0.f, 0.f, 0.f};
        aw = __builtin_amdgcn_mfma_f32_16x16x32_bf16(Ahh.s8, Bwh, aw, 0, 0, 0);
        aw = __builtin_amdgcn_mfma_f32_16x16x32_bf16(Ahl.s8, Bwh, aw, 0, 0, 0);
        aw = __builtin_amdgcn_mfma_f32_16x16x32_bf16(Ahh.s8, Bwl, aw, 0, 0, 0);
        if (u0 == 0) {
            #pragma unroll
            for (int r = 0; r < 4; ++r)
                out_lds[(q * 4 + r) * TS + 49] = aw[r] + bout;
        }
    }

    __syncthreads();
    // ---- coalesced flush: 800 contiguous floats ----
    {
        float4* od = (float4*)(out + b0 * 50);
        const float4* os = (const float4*)out_lds;
        for (int i = tid; i < 200; i += 128) od[i] = os[i];
    }
}

extern "C" void kernel_launch(void* const* d_in, const int* in_sizes, int n_in,
                              void* d_out, int out_size, void* d_ws, size_t ws_size,
                              hipStream_t stream) {
    const float* x     = (const float*)d_in[0];
    const float* W_ih  = (const float*)d_in[1];
    const float* W_hh  = (const float*)d_in[2];
    const float* b_ih  = (const float*)d_in[3];
    const float* b_hh  = (const float*)d_in[4];
    const float* W_out = (const float*)d_in[5];
    const float* b_out = (const float*)d_in[6];
    const float* h0    = (const float*)d_in[7];
    const float* c0    = (const float*)d_in[8];
    float* out = (float*)d_out;

    dim3 grid(32768 / 16), block(128);
    lsnn_kernel<<<grid, block, 0, stream>>>(x, W_ih, W_hh, b_ih, b_hh,
                                            W_out, b_out, h0, c0, out);
}